// Round 4
// baseline (216.543 us; speedup 1.0000x reference)
//
#include <hip/hip_runtime.h>
#include <hip/hip_bf16.h>

// sLSTM cell: B=8192, I=1024, H=1024.
// G = [x|h] @ [W|R]^T  (M=8192, N=4096=4 gates x 1024, K=2048), then elementwise.
// Round 4: (1) grid=256 (1 block/CU), each block loops 2 brow tiles; rep-1 prologue
// issued before rep-0 epilogue so EP stores/loads overlap GEMM. (2) XCD-aware
// swizzle: each XCD's 32 CUs share 2 Wp panels (2 MB -> L2-resident B staging).
// K-loop body identical to validated round 3 (3 barriers/K-tile, 0 bank conflicts).

#define B_SZ 8192
#define K_SZ 2048
#define H_SZ 1024
#define OUTSTRIDE 8388608   // B_SZ*H_SZ
#define EPSF 1e-7f
#define NT 32               // K_SZ / 64
#define ATILE 16384         // ushorts per A K-tile buffer (256 rows x 64 k)
#define BTILE 16384
#define AREPOFF 524288      // 256 rows * 2048 k (ushorts) between rep brow tiles

using bf16x8 = __attribute__((ext_vector_type(8))) short;
using f32x4  = __attribute__((ext_vector_type(4))) float;

__device__ inline ushort f2bf(float f) {
    uint u = __float_as_uint(f);
    u = (u + 0x7fffu + ((u >> 16) & 1u)) >> 16;
    return (ushort)u;
}

#if __has_builtin(__builtin_amdgcn_rcpf)
__device__ inline float frcp(float x) { return __builtin_amdgcn_rcpf(x); }
#else
__device__ inline float frcp(float x) { return 1.0f / x; }
#endif
__device__ inline float fsigmoid(float x) { return frcp(1.0f + __expf(-x)); }
__device__ inline float ftanh(float x) {
    return 1.0f - 2.0f * frcp(__expf(2.0f * x) + 1.0f);
}

#define GLOAD16(gp, lp)                                                              \
    __builtin_amdgcn_global_load_lds((const __attribute__((address_space(1))) void*)(gp), \
                                     (__attribute__((address_space(3))) void*)(lp),  \
                                     16, 0, 0)

#define BAR() do { asm volatile("" ::: "memory"); __builtin_amdgcn_s_barrier(); \
                   asm volatile("" ::: "memory"); } while (0)
#define WAITVM(n) asm volatile("s_waitcnt vmcnt(" #n ")" ::: "memory")

// ---------------- pack kernels (unchanged, validated) ----------------

__global__ void pack_xh(const float* __restrict__ x, const float* __restrict__ h,
                        ushort* __restrict__ XH) {
    const int b  = blockIdx.x;
    const int kc = threadIdx.x;
    const float* src = (kc < 128) ? (x + (size_t)b * 1024 + kc * 8)
                                  : (h + (size_t)b * 1024 + (kc - 128) * 8);
    float4 v0 = ((const float4*)src)[0];
    float4 v1 = ((const float4*)src)[1];
    uint4 o;
    o.x = (uint)f2bf(v0.x) | ((uint)f2bf(v0.y) << 16);
    o.y = (uint)f2bf(v0.z) | ((uint)f2bf(v0.w) << 16);
    o.z = (uint)f2bf(v1.x) | ((uint)f2bf(v1.y) << 16);
    o.w = (uint)f2bf(v1.z) | ((uint)f2bf(v1.w) << 16);
    ((uint4*)(XH + (size_t)b * 2048 + kc * 8))[0] = o;
}

__global__ void pack_w(const float* __restrict__ w_i, const float* __restrict__ r_i,
                       const float* __restrict__ w_f, const float* __restrict__ r_f,
                       const float* __restrict__ w_o, const float* __restrict__ r_o,
                       const float* __restrict__ w_z, const float* __restrict__ r_z,
                       ushort* __restrict__ Wp) {
    const int n  = blockIdx.x;
    const int g  = n >> 10, hr = n & 1023;
    const int kc = threadIdx.x;
    const float* wsel = (g == 0) ? w_i : (g == 1) ? w_f : (g == 2) ? w_o : w_z;
    const float* rsel = (g == 0) ? r_i : (g == 1) ? r_f : (g == 2) ? r_o : r_z;
    const float* src = (kc < 128) ? (wsel + (size_t)hr * 1024 + kc * 8)
                                  : (rsel + (size_t)hr * 1024 + (kc - 128) * 8);
    float4 v0 = ((const float4*)src)[0];
    float4 v1 = ((const float4*)src)[1];
    uint4 o;
    o.x = (uint)f2bf(v0.x) | ((uint)f2bf(v0.y) << 16);
    o.y = (uint)f2bf(v0.z) | ((uint)f2bf(v0.w) << 16);
    o.z = (uint)f2bf(v1.x) | ((uint)f2bf(v1.y) << 16);
    o.w = (uint)f2bf(v1.z) | ((uint)f2bf(v1.w) << 16);
    ((uint4*)(Wp + (size_t)n * 2048 + kc * 8))[0] = o;
}

// ---------------- fused GEMM + sLSTM epilogue ----------------
// LDS layout per K-tile: slot(row, c) = row*8 + (c ^ (row&7)), 16B slots.
// Staging writes linear slots (global src pre-swizzled); reads apply the XOR.
// Barrier set (3/K-tile): BAR_a after B-reads consumed, BAR_b after A-reads
// consumed, BAR_c after WAITVM (tile t+1 landed).

__global__ __launch_bounds__(512, 2)
void slstm_fused(const ushort* __restrict__ XH, const ushort* __restrict__ Wp,
                 const float* __restrict__ c_prev, const float* __restrict__ n_prev,
                 const float* __restrict__ m_prev,
                 const float* __restrict__ bi_, const float* __restrict__ bf_,
                 const float* __restrict__ bo_, const float* __restrict__ bz_,
                 float* __restrict__ out) {
    __shared__ __align__(16) ushort Alds[2 * ATILE];   // 64 KB
    __shared__ __align__(16) ushort Blds[2 * BTILE];   // 64 KB

    const int tid  = threadIdx.x;
    const int lane = tid & 63;
    const int wave = tid >> 6;
    const int wm = wave >> 2, wn = wave & 3;   // 2 x 4 waves
    const int l16 = lane & 15, lk = lane >> 4;

    // XCD-aware swizzle: 256 blocks = 8 XCDs x 32 CUs. Each XCD handles 2 hcol
    // panels (Wp slices, 2 MB total -> L2-resident) x 16 brow-pairs.
    const int bid = blockIdx.x;
    const int xcd = bid & 7, idx = bid >> 3;
    const int hcol      = (xcd * 2 + (idx >> 4)) * 64;
    const int brow_base = (idx & 15) * 512;            // rep r: brow = base + r*256

    // per-lane pre-swizzled staging source pointers (rep-0 A base)
    const ushort* srcA[4];
    const ushort* srcB[4];
#pragma unroll
    for (int c = 0; c < 4; ++c) {
        const int s = c * 512 + tid;          // linear 16B slot
        const int row = s >> 3, cph = s & 7;
        const int cl = cph ^ (row & 7);       // logical chunk
        srcA[c] = XH + (size_t)(brow_base + row) * 2048 + cl * 8;
        const int g = row >> 6, hh = row & 63;
        srcB[c] = Wp + (size_t)(g * 1024 + hcol + hh) * 2048 + cl * 8;
    }

    // fragment read offsets (ushort units); row&7 == l16&7 for all frag rows
    const int x7  = l16 & 7;
    const int cA0 = ((0 + lk) ^ x7) * 8;      // kh=0 phys chunk
    const int cA1 = ((4 + lk) ^ x7) * 8;      // kh=1 phys chunk
    const int abase = (wm * 128 + l16) * 64;  // + mf*1024 + cA{kh}
    const int bbase = (wn * 16 + l16) * 64;   // + g*4096  + cA{kh}

#define STAGE(srcarr, aoff, ldsbase, tko)                                \
    do {                                                                 \
        _Pragma("unroll")                                                \
        for (int c = 0; c < 4; ++c)                                      \
            GLOAD16(srcarr[c] + (aoff) + (tko), (ldsbase) + (c * 512 + wave * 64) * 8); \
    } while (0)

    // prologue rep0: tile0 -> buf0, tile1 -> buf1
    STAGE(srcB, 0, Blds, 0);
    STAGE(srcA, 0, Alds, 0);
    STAGE(srcB, 0, Blds + BTILE, 64);
    STAGE(srcA, 0, Alds + ATILE, 64);
    WAITVM(8);
    BAR();

    for (int rep = 0; rep < 2; ++rep) {
        const size_t aoff = (size_t)rep * AREPOFF;

        f32x4 acc[8][4];                          // [mf][gate]
#pragma unroll
        for (int m = 0; m < 8; ++m)
#pragma unroll
            for (int g = 0; g < 4; ++g)
                acc[m][g] = (f32x4){0.f, 0.f, 0.f, 0.f};

        bf16x8 a[4][2], b[4][2];

        for (int t = 0; t < NT; ++t) {
            const ushort* Ab = Alds + (t & 1) * ATILE;
            const ushort* Bb = Blds + (t & 1) * BTILE;
            ushort* Aw = (ushort*)Ab;             // stage dest for tile t+2
            ushort* Bw = (ushort*)Bb;
            const int tko = (t + 2) * 64;
            const bool doStage = (t < NT - 2);

            // ---- P0: read A(mf0-3) + B(g0-1); MFMA mf0-3 x g0-1 ----
#pragma unroll
            for (int m = 0; m < 4; ++m) {
                a[m][0] = *(const bf16x8*)(Ab + abase + m * 1024 + cA0);
                a[m][1] = *(const bf16x8*)(Ab + abase + m * 1024 + cA1);
            }
#pragma unroll
            for (int g = 0; g < 2; ++g) {
                b[g][0] = *(const bf16x8*)(Bb + bbase + g * 4096 + cA0);
                b[g][1] = *(const bf16x8*)(Bb + bbase + g * 4096 + cA1);
            }
            __builtin_amdgcn_s_setprio(1);
#pragma unroll
            for (int m = 0; m < 4; ++m)
#pragma unroll
                for (int g = 0; g < 2; ++g) {
                    acc[m][g] = __builtin_amdgcn_mfma_f32_16x16x32_bf16(a[m][0], b[g][0], acc[m][g], 0, 0, 0);
                    acc[m][g] = __builtin_amdgcn_mfma_f32_16x16x32_bf16(a[m][1], b[g][1], acc[m][g], 0, 0, 0);
                }
            __builtin_amdgcn_s_setprio(0);

            // ---- P1: read B(g2-3); MFMA mf0-3 x g2-3; BAR_a ----
#pragma unroll
            for (int g = 2; g < 4; ++g) {
                b[g][0] = *(const bf16x8*)(Bb + bbase + g * 4096 + cA0);
                b[g][1] = *(const bf16x8*)(Bb + bbase + g * 4096 + cA1);
            }
            __builtin_amdgcn_s_setprio(1);
#pragma unroll
            for (int m = 0; m < 4; ++m)
#pragma unroll
                for (int g = 2; g < 4; ++g) {
                    acc[m][g] = __builtin_amdgcn_mfma_f32_16x16x32_bf16(a[m][0], b[g][0], acc[m][g], 0, 0, 0);
                    acc[m][g] = __builtin_amdgcn_mfma_f32_16x16x32_bf16(a[m][1], b[g][1], acc[m][g], 0, 0, 0);
                }
            __builtin_amdgcn_s_setprio(0);
            BAR();   // all B-region reads done -> B stage may begin

            // ---- P2: read A(mf4-7); stage B(t+2); MFMA mf4-7 x g0-1; BAR_b ----
#pragma unroll
            for (int m = 0; m < 4; ++m) {
                a[m][0] = *(const bf16x8*)(Ab + abase + (m + 4) * 1024 + cA0);
                a[m][1] = *(const bf16x8*)(Ab + abase + (m + 4) * 1024 + cA1);
            }
            if (doStage) STAGE(srcB, 0, Bw, tko);
            __builtin_amdgcn_s_setprio(1);
#pragma unroll
            for (int m = 0; m < 4; ++m)
#pragma unroll
                for (int g = 0; g < 2; ++g) {
                    acc[m + 4][g] = __builtin_amdgcn_mfma_f32_16x16x32_bf16(a[m][0], b[g][0], acc[m + 4][g], 0, 0, 0);
                    acc[m + 4][g] = __builtin_amdgcn_mfma_f32_16x16x32_bf16(a[m][1], b[g][1], acc[m + 4][g], 0, 0, 0);
                }
            __builtin_amdgcn_s_setprio(0);
            BAR();   // all A-region reads done -> A stage may begin

            // ---- P3: stage A(t+2); MFMA mf4-7 x g2-3; WAITVM; BAR_c ----
            if (doStage) STAGE(srcA, aoff, Aw, tko);
            __builtin_amdgcn_s_setprio(1);
#pragma unroll
            for (int m = 0; m < 4; ++m)
#pragma unroll
                for (int g = 2; g < 4; ++g) {
                    acc[m + 4][g] = __builtin_amdgcn_mfma_f32_16x16x32_bf16(a[m][0], b[g][0], acc[m + 4][g], 0, 0, 0);
                    acc[m + 4][g] = __builtin_amdgcn_mfma_f32_16x16x32_bf16(a[m][1], b[g][1], acc[m + 4][g], 0, 0, 0);
                }
            __builtin_amdgcn_s_setprio(0);
            if (t < NT - 2) { WAITVM(8); } else { WAITVM(0); }
            BAR();
        }

        // issue rep-1 prologue BEFORE the epilogue so staging overlaps EP and
        // EP stores drain under rep-1's GEMM. (All LDS reads drained: t=NT-1
        // ends with WAITVM(0)+BAR.)
        if (rep == 0) {
            STAGE(srcB, 0, Blds, 0);
            STAGE(srcA, AREPOFF, Alds, 0);
            STAGE(srcB, 0, Blds + BTILE, 64);
            STAGE(srcA, AREPOFF, Alds + ATILE, 64);
        }

        // ---- in-register sLSTM epilogue (fast-math) ----
        const int brow = brow_base + rep * 256;
        const int h = hcol + wn * 16 + l16;
        const float vbi = bi_[h], vbf = bf_[h], vbo = bo_[h], vbz = bz_[h];
#pragma unroll
        for (int mf = 0; mf < 8; ++mf) {
#pragma unroll
            for (int r = 0; r < 4; ++r) {
                const int bb = brow + wm * 128 + mf * 16 + lk * 4 + r;
                const size_t idx2 = (size_t)bb * H_SZ + h;
                float it = acc[mf][0][r] + vbi;
                float ft = acc[mf][1][r] + vbf;
                float ot = acc[mf][2][r] + vbo;
                float zt = acc[mf][3][r] + vbz;
                it = fminf(fmaxf(it, -50.f), 50.f);
                ft = fminf(fmaxf(ft, -50.f), 50.f);
                ot = fminf(fmaxf(ot, -50.f), 50.f);
                zt = fminf(fmaxf(zt, -50.f), 50.f);
                float f_sig = fsigmoid(ft);
                f_sig = fminf(fmaxf(f_sig, EPSF), 1.0f - EPSF);
                const float log_f = __logf(f_sig);
                const float li  = (it > -6.9f) ? it : __logf(__expf(it) + EPSF);
                const float mp  = m_prev[idx2];
                const float m_t = fmaxf(log_f + mp, li);
                const float i_pr = __expf(it - m_t);
                const float f_pr = __expf(log_f + mp - m_t);
                const float c_t  = f_pr * c_prev[idx2] + i_pr * ftanh(zt);
                const float n_t  = f_pr * n_prev[idx2] + i_pr;
                const float c_hat = c_t * frcp(n_t + EPSF);
                const float h_t   = fsigmoid(ot) * ftanh(c_hat);
                out[idx2]                 = h_t;
                out[idx2 + OUTSTRIDE]     = h_t;
                out[idx2 + 2 * OUTSTRIDE] = c_t;
                out[idx2 + 3 * OUTSTRIDE] = n_t;
                out[idx2 + 4 * OUTSTRIDE] = m_t;
            }
        }

        if (rep == 0) {
            WAITVM(8);   // prologue drained (leaves newest 8 EP stores in flight)
            BAR();
        }
    }
#undef STAGE
}

extern "C" void kernel_launch(void* const* d_in, const int* in_sizes, int n_in,
                              void* d_out, int out_size, void* d_ws, size_t ws_size,
                              hipStream_t stream) {
    const float* x   = (const float*)d_in[0];
    const float* hp  = (const float*)d_in[1];
    const float* cp  = (const float*)d_in[2];
    const float* np_ = (const float*)d_in[3];
    const float* mp  = (const float*)d_in[4];
    const float* w_i = (const float*)d_in[5];
    const float* r_i = (const float*)d_in[6];
    const float* b_i = (const float*)d_in[7];
    const float* w_f = (const float*)d_in[8];
    const float* r_f = (const float*)d_in[9];
    const float* b_f = (const float*)d_in[10];
    const float* w_o = (const float*)d_in[11];
    const float* r_o = (const float*)d_in[12];
    const float* b_o = (const float*)d_in[13];
    const float* w_z = (const float*)d_in[14];
    const float* r_z = (const float*)d_in[15];
    const float* b_z = (const float*)d_in[16];

    ushort* XH = (ushort*)d_ws;                       // 32 MB
    ushort* Wp = XH + (size_t)B_SZ * K_SZ;            // 16 MB

    pack_xh<<<B_SZ, 256, 0, stream>>>(x, hp, XH);
    pack_w<<<4096, 256, 0, stream>>>(w_i, r_i, w_f, r_f, w_o, r_o, w_z, r_z, Wp);
    slstm_fused<<<256, 512, 0, stream>>>(
        XH, Wp, cp, np_, mp, b_i, b_f, b_o, b_z, (float*)d_out);
}

// Round 5
// 202.131 us; speedup vs baseline: 1.0713x; 1.0713x over previous
//
#include <hip/hip_runtime.h>
#include <hip/hip_bf16.h>

// sLSTM cell: B=8192, I=1024, H=1024.
// G = [x|h] @ [W|R]^T  (M=8192, N=4096=4 gates x 1024, K=2048), then elementwise.
// Round 5: revert round-4 grid experiment (back to 512 blocks, dim3(32,16)).
// New: one-phase-ahead fragment reads — issue phase p+1's ds_reads before phase
// p's MFMA cluster so the LDS pipe overlaps the matrix pipe. Same math order,
// same 3-barrier hazard structure as validated round 3.

#define B_SZ 8192
#define K_SZ 2048
#define H_SZ 1024
#define OUTSTRIDE 8388608   // B_SZ*H_SZ
#define EPSF 1e-7f
#define NT 32               // K_SZ / 64
#define ATILE 16384         // ushorts per A K-tile buffer (256 rows x 64 k)
#define BTILE 16384

using bf16x8 = __attribute__((ext_vector_type(8))) short;
using f32x4  = __attribute__((ext_vector_type(4))) float;

__device__ inline ushort f2bf(float f) {
    uint u = __float_as_uint(f);
    u = (u + 0x7fffu + ((u >> 16) & 1u)) >> 16;
    return (ushort)u;
}

#if __has_builtin(__builtin_amdgcn_rcpf)
__device__ inline float frcp(float x) { return __builtin_amdgcn_rcpf(x); }
#else
__device__ inline float frcp(float x) { return 1.0f / x; }
#endif
__device__ inline float fsigmoid(float x) { return frcp(1.0f + __expf(-x)); }
__device__ inline float ftanh(float x) {
    return 1.0f - 2.0f * frcp(__expf(2.0f * x) + 1.0f);
}

#define GLOAD16(gp, lp)                                                              \
    __builtin_amdgcn_global_load_lds((const __attribute__((address_space(1))) void*)(gp), \
                                     (__attribute__((address_space(3))) void*)(lp),  \
                                     16, 0, 0)

#define BAR() do { asm volatile("" ::: "memory"); __builtin_amdgcn_s_barrier(); \
                   asm volatile("" ::: "memory"); } while (0)
#define WAITVM(n) asm volatile("s_waitcnt vmcnt(" #n ")" ::: "memory")

// ---------------- pack kernels (unchanged, validated) ----------------

__global__ void pack_xh(const float* __restrict__ x, const float* __restrict__ h,
                        ushort* __restrict__ XH) {
    const int b  = blockIdx.x;
    const int kc = threadIdx.x;
    const float* src = (kc < 128) ? (x + (size_t)b * 1024 + kc * 8)
                                  : (h + (size_t)b * 1024 + (kc - 128) * 8);
    float4 v0 = ((const float4*)src)[0];
    float4 v1 = ((const float4*)src)[1];
    uint4 o;
    o.x = (uint)f2bf(v0.x) | ((uint)f2bf(v0.y) << 16);
    o.y = (uint)f2bf(v0.z) | ((uint)f2bf(v0.w) << 16);
    o.z = (uint)f2bf(v1.x) | ((uint)f2bf(v1.y) << 16);
    o.w = (uint)f2bf(v1.z) | ((uint)f2bf(v1.w) << 16);
    ((uint4*)(XH + (size_t)b * 2048 + kc * 8))[0] = o;
}

__global__ void pack_w(const float* __restrict__ w_i, const float* __restrict__ r_i,
                       const float* __restrict__ w_f, const float* __restrict__ r_f,
                       const float* __restrict__ w_o, const float* __restrict__ r_o,
                       const float* __restrict__ w_z, const float* __restrict__ r_z,
                       ushort* __restrict__ Wp) {
    const int n  = blockIdx.x;
    const int g  = n >> 10, hr = n & 1023;
    const int kc = threadIdx.x;
    const float* wsel = (g == 0) ? w_i : (g == 1) ? w_f : (g == 2) ? w_o : w_z;
    const float* rsel = (g == 0) ? r_i : (g == 1) ? r_f : (g == 2) ? r_o : r_z;
    const float* src = (kc < 128) ? (wsel + (size_t)hr * 1024 + kc * 8)
                                  : (rsel + (size_t)hr * 1024 + (kc - 128) * 8);
    float4 v0 = ((const float4*)src)[0];
    float4 v1 = ((const float4*)src)[1];
    uint4 o;
    o.x = (uint)f2bf(v0.x) | ((uint)f2bf(v0.y) << 16);
    o.y = (uint)f2bf(v0.z) | ((uint)f2bf(v0.w) << 16);
    o.z = (uint)f2bf(v1.x) | ((uint)f2bf(v1.y) << 16);
    o.w = (uint)f2bf(v1.z) | ((uint)f2bf(v1.w) << 16);
    ((uint4*)(Wp + (size_t)n * 2048 + kc * 8))[0] = o;
}

// ---------------- fused GEMM + sLSTM epilogue ----------------
// LDS layout per K-tile: slot(row, c) = row*8 + (c ^ (row&7)), 16B slots.
// Staging writes linear slots (global src pre-swizzled); reads apply the XOR.
// Barrier set (3/K-tile):
//   BAR_a (end P1): b01 consumed in P0, b23 consumed in P1 -> B-region free
//   BAR_b (end P2): a_lo consumed in P1, a_hi consumed in P2 -> A-region free
//   BAR_c (end P3, after WAITVM): tile t+1 landed for all waves
// Fragment reads are issued ONE PHASE AHEAD of their consuming MFMA cluster:
//   pre-tile: a_lo(t), b01(t) | P0: issue b23(t) | P1: issue a_hi(t)
//   post-BAR_c: a_lo(t+1), b01(t+1)

__global__ __launch_bounds__(512, 2)
void slstm_fused(const ushort* __restrict__ XH, const ushort* __restrict__ Wp,
                 const float* __restrict__ c_prev, const float* __restrict__ n_prev,
                 const float* __restrict__ m_prev,
                 const float* __restrict__ bi_, const float* __restrict__ bf_,
                 const float* __restrict__ bo_, const float* __restrict__ bz_,
                 float* __restrict__ out) {
    __shared__ __align__(16) ushort Alds[2 * ATILE];   // 64 KB
    __shared__ __align__(16) ushort Blds[2 * BTILE];   // 64 KB

    const int tid  = threadIdx.x;
    const int lane = tid & 63;
    const int wave = tid >> 6;
    const int wm = wave >> 2, wn = wave & 3;   // 2 x 4 waves
    const int l16 = lane & 15, lk = lane >> 4;

    const int brow = blockIdx.x * 256;
    const int hcol = blockIdx.y * 64;

    // per-lane pre-swizzled staging source pointers (advance by 64 ushorts/tile)
    const ushort* srcA[4];
    const ushort* srcB[4];
#pragma unroll
    for (int c = 0; c < 4; ++c) {
        const int s = c * 512 + tid;          // linear 16B slot
        const int row = s >> 3, cph = s & 7;
        const int cl = cph ^ (row & 7);       // logical chunk
        srcA[c] = XH + (size_t)(brow + row) * 2048 + cl * 8;
        const int g = row >> 6, hh = row & 63;
        srcB[c] = Wp + (size_t)(g * 1024 + hcol + hh) * 2048 + cl * 8;
    }

    // fragment read offsets (ushort units); row&7 == l16&7 for all frag rows
    const int x7  = l16 & 7;
    const int cA0 = ((0 + lk) ^ x7) * 8;      // kh=0 phys chunk
    const int cA1 = ((4 + lk) ^ x7) * 8;      // kh=1 phys chunk
    const int abase = (wm * 128 + l16) * 64;  // + mf*1024 + cA{kh}
    const int bbase = (wn * 16 + l16) * 64;   // + g*4096  + cA{kh}

    f32x4 acc[8][4];                          // [mf][gate]
#pragma unroll
    for (int m = 0; m < 8; ++m)
#pragma unroll
        for (int g = 0; g < 4; ++g)
            acc[m][g] = (f32x4){0.f, 0.f, 0.f, 0.f};

#define STAGE(srcarr, ldsbase, tko)                                      \
    do {                                                                 \
        _Pragma("unroll")                                                \
        for (int c = 0; c < 4; ++c)                                      \
            GLOAD16(srcarr[c] + (tko), (ldsbase) + (c * 512 + wave * 64) * 8); \
    } while (0)

    // prologue: tile0 -> buf0, tile1 -> buf1; wait tile0 (8 newest stay in flight)
    STAGE(srcB, Blds, 0);
    STAGE(srcA, Alds, 0);
    STAGE(srcB, Blds + BTILE, 64);
    STAGE(srcA, Alds + ATILE, 64);
    WAITVM(8);
    BAR();

    bf16x8 a_lo[4][2], a_hi[4][2], b01[2][2], b23[2][2];

    // initial frag reads: tile 0, buf 0
#pragma unroll
    for (int m = 0; m < 4; ++m) {
        a_lo[m][0] = *(const bf16x8*)(Alds + abase + m * 1024 + cA0);
        a_lo[m][1] = *(const bf16x8*)(Alds + abase + m * 1024 + cA1);
    }
#pragma unroll
    for (int g = 0; g < 2; ++g) {
        b01[g][0] = *(const bf16x8*)(Blds + bbase + g * 4096 + cA0);
        b01[g][1] = *(const bf16x8*)(Blds + bbase + g * 4096 + cA1);
    }

    for (int t = 0; t < NT; ++t) {
        const ushort* Ab = Alds + (t & 1) * ATILE;
        const ushort* Bb = Blds + (t & 1) * BTILE;
        ushort* Aw = (ushort*)Ab;             // stage dest for tile t+2 (same parity)
        ushort* Bw = (ushort*)Bb;
        const int tko = (t + 2) * 64;
        const bool doStage = (t < NT - 2);

        // ---- P0: issue b23(t) reads; MFMA mf0-3 x g0-1 ----
#pragma unroll
        for (int g = 0; g < 2; ++g) {
            b23[g][0] = *(const bf16x8*)(Bb + bbase + (g + 2) * 4096 + cA0);
            b23[g][1] = *(const bf16x8*)(Bb + bbase + (g + 2) * 4096 + cA1);
        }
        __builtin_amdgcn_s_setprio(1);
#pragma unroll
        for (int m = 0; m < 4; ++m)
#pragma unroll
            for (int g = 0; g < 2; ++g) {
                acc[m][g] = __builtin_amdgcn_mfma_f32_16x16x32_bf16(a_lo[m][0], b01[g][0], acc[m][g], 0, 0, 0);
                acc[m][g] = __builtin_amdgcn_mfma_f32_16x16x32_bf16(a_lo[m][1], b01[g][1], acc[m][g], 0, 0, 0);
            }
        __builtin_amdgcn_s_setprio(0);

        // ---- P1: issue a_hi(t) reads; MFMA mf0-3 x g2-3; BAR_a ----
#pragma unroll
        for (int m = 0; m < 4; ++m) {
            a_hi[m][0] = *(const bf16x8*)(Ab + abase + (m + 4) * 1024 + cA0);
            a_hi[m][1] = *(const bf16x8*)(Ab + abase + (m + 4) * 1024 + cA1);
        }
        __builtin_amdgcn_s_setprio(1);
#pragma unroll
        for (int m = 0; m < 4; ++m)
#pragma unroll
            for (int g = 0; g < 2; ++g) {
                acc[m][g + 2] = __builtin_amdgcn_mfma_f32_16x16x32_bf16(a_lo[m][0], b23[g][0], acc[m][g + 2], 0, 0, 0);
                acc[m][g + 2] = __builtin_amdgcn_mfma_f32_16x16x32_bf16(a_lo[m][1], b23[g][1], acc[m][g + 2], 0, 0, 0);
            }
        __builtin_amdgcn_s_setprio(0);
        BAR();   // BAR_a: all B-region reads complete -> B stage may begin

        // ---- P2: stage B(t+2); MFMA mf4-7 x g0-1; BAR_b ----
        if (doStage) STAGE(srcB, Bw, tko);
        __builtin_amdgcn_s_setprio(1);
#pragma unroll
        for (int m = 0; m < 4; ++m)
#pragma unroll
            for (int g = 0; g < 2; ++g) {
                acc[m + 4][g] = __builtin_amdgcn_mfma_f32_16x16x32_bf16(a_hi[m][0], b01[g][0], acc[m + 4][g], 0, 0, 0);
                acc[m + 4][g] = __builtin_amdgcn_mfma_f32_16x16x32_bf16(a_hi[m][1], b01[g][1], acc[m + 4][g], 0, 0, 0);
            }
        __builtin_amdgcn_s_setprio(0);
        BAR();   // BAR_b: all A-region reads complete -> A stage may begin

        // ---- P3: stage A(t+2); MFMA mf4-7 x g2-3; WAITVM; BAR_c ----
        if (doStage) STAGE(srcA, Aw, tko);
        __builtin_amdgcn_s_setprio(1);
#pragma unroll
        for (int m = 0; m < 4; ++m)
#pragma unroll
            for (int g = 0; g < 2; ++g) {
                acc[m + 4][g + 2] = __builtin_amdgcn_mfma_f32_16x16x32_bf16(a_hi[m][0], b23[g][0], acc[m + 4][g + 2], 0, 0, 0);
                acc[m + 4][g + 2] = __builtin_amdgcn_mfma_f32_16x16x32_bf16(a_hi[m][1], b23[g][1], acc[m + 4][g + 2], 0, 0, 0);
            }
        __builtin_amdgcn_s_setprio(0);
        // ensure tile t+1 landed; keep tile t+2's 8 loads in flight
        if (t < NT - 2) { WAITVM(8); } else { WAITVM(0); }
        BAR();   // BAR_c

        // ---- next-tile frag reads (a_lo, b01 of tile t+1) ----
        if (t < NT - 1) {
            const ushort* An = Alds + ((t + 1) & 1) * ATILE;
            const ushort* Bn = Blds + ((t + 1) & 1) * BTILE;
#pragma unroll
            for (int m = 0; m < 4; ++m) {
                a_lo[m][0] = *(const bf16x8*)(An + abase + m * 1024 + cA0);
                a_lo[m][1] = *(const bf16x8*)(An + abase + m * 1024 + cA1);
            }
#pragma unroll
            for (int g = 0; g < 2; ++g) {
                b01[g][0] = *(const bf16x8*)(Bn + bbase + g * 4096 + cA0);
                b01[g][1] = *(const bf16x8*)(Bn + bbase + g * 4096 + cA1);
            }
        }
    }
#undef STAGE

    // ---- in-register sLSTM epilogue (fast-math) ----
    const int h = hcol + wn * 16 + l16;
    const float vbi = bi_[h], vbf = bf_[h], vbo = bo_[h], vbz = bz_[h];
#pragma unroll
    for (int mf = 0; mf < 8; ++mf) {
#pragma unroll
        for (int r = 0; r < 4; ++r) {
            const int bb = brow + wm * 128 + mf * 16 + lk * 4 + r;
            const size_t idx2 = (size_t)bb * H_SZ + h;
            float it = acc[mf][0][r] + vbi;
            float ft = acc[mf][1][r] + vbf;
            float ot = acc[mf][2][r] + vbo;
            float zt = acc[mf][3][r] + vbz;
            it = fminf(fmaxf(it, -50.f), 50.f);
            ft = fminf(fmaxf(ft, -50.f), 50.f);
            ot = fminf(fmaxf(ot, -50.f), 50.f);
            zt = fminf(fmaxf(zt, -50.f), 50.f);
            float f_sig = fsigmoid(ft);
            f_sig = fminf(fmaxf(f_sig, EPSF), 1.0f - EPSF);
            const float log_f = __logf(f_sig);
            const float li  = (it > -6.9f) ? it : __logf(__expf(it) + EPSF);
            const float mp  = m_prev[idx2];
            const float m_t = fmaxf(log_f + mp, li);
            const float i_pr = __expf(it - m_t);
            const float f_pr = __expf(log_f + mp - m_t);
            const float c_t  = f_pr * c_prev[idx2] + i_pr * ftanh(zt);
            const float n_t  = f_pr * n_prev[idx2] + i_pr;
            const float c_hat = c_t * frcp(n_t + EPSF);
            const float h_t   = fsigmoid(ot) * ftanh(c_hat);
            out[idx2]                 = h_t;
            out[idx2 + OUTSTRIDE]     = h_t;
            out[idx2 + 2 * OUTSTRIDE] = c_t;
            out[idx2 + 3 * OUTSTRIDE] = n_t;
            out[idx2 + 4 * OUTSTRIDE] = m_t;
        }
    }
}

extern "C" void kernel_launch(void* const* d_in, const int* in_sizes, int n_in,
                              void* d_out, int out_size, void* d_ws, size_t ws_size,
                              hipStream_t stream) {
    const float* x   = (const float*)d_in[0];
    const float* hp  = (const float*)d_in[1];
    const float* cp  = (const float*)d_in[2];
    const float* np_ = (const float*)d_in[3];
    const float* mp  = (const float*)d_in[4];
    const float* w_i = (const float*)d_in[5];
    const float* r_i = (const float*)d_in[6];
    const float* b_i = (const float*)d_in[7];
    const float* w_f = (const float*)d_in[8];
    const float* r_f = (const float*)d_in[9];
    const float* b_f = (const float*)d_in[10];
    const float* w_o = (const float*)d_in[11];
    const float* r_o = (const float*)d_in[12];
    const float* b_o = (const float*)d_in[13];
    const float* w_z = (const float*)d_in[14];
    const float* r_z = (const float*)d_in[15];
    const float* b_z = (const float*)d_in[16];

    ushort* XH = (ushort*)d_ws;                       // 32 MB
    ushort* Wp = XH + (size_t)B_SZ * K_SZ;            // 16 MB

    pack_xh<<<B_SZ, 256, 0, stream>>>(x, hp, XH);
    pack_w<<<4096, 256, 0, stream>>>(w_i, r_i, w_f, r_f, w_o, r_o, w_z, r_z, Wp);
    slstm_fused<<<dim3(32, 16), 512, 0, stream>>>(
        XH, Wp, cp, np_, mp, b_i, b_f, b_o, b_z, (float*)d_out);
}